// Round 1
// baseline (3005.037 us; speedup 1.0000x reference)
//
#include <hip/hip_runtime.h>
#include <math.h>

#define WIDTH 192
#define KNN 12
#define NSPLIT 8
#define TILE 1024

// ---------------- precompute: fold z into biases (bias0, gamma, beta) --------
__global__ __launch_bounds__(256) void precompute_kernel(
    const float* __restrict__ z, const float* __restrict__ Wp, const float* __restrict__ bp,
    const float* __restrict__ Wg, const float* __restrict__ bg,
    const float* __restrict__ Wb, const float* __restrict__ bb,
    float* __restrict__ bias0, float* __restrict__ gammaB, float* __restrict__ betaB)
{
    __shared__ float zs[64];
    int t = threadIdx.x;
    if (t < 64) zs[t] = z[t];
    __syncthreads();
    if (t < WIDTH) {
        float acc = bp[t];
        for (int k = 0; k < 64; ++k) acc += zs[k] * Wp[(51 + k) * WIDTH + t];
        bias0[t] = acc;
        for (int l = 0; l < 4; ++l) {
            float g = bg[l * WIDTH + t];
            float b = bb[l * WIDTH + t];
            for (int k = 0; k < 64; ++k) {
                g += zs[k] * Wg[(l * 64 + k) * WIDTH + t];
                b += zs[k] * Wb[(l * 64 + k) * WIDTH + t];
            }
            gammaB[l * WIDTH + t] = g;
            betaB[l * WIDTH + t] = b;
        }
    }
}

// ---------------- kNN: partial top-12 over 1/NSPLIT of candidates ------------
// Tie semantics must match jax.lax.top_k(-d, k): keep k smallest by
// lexicographic (d, index). Replace worst iff (d,idx) < (wd,wi).
__global__ __launch_bounds__(256) void knn_partial_kernel(
    const float* __restrict__ x, int n, float* __restrict__ pd, int* __restrict__ pi)
{
    int i = blockIdx.x * 256 + threadIdx.x;
    int split = blockIdx.y;
    int csz = n / NSPLIT;
    __shared__ float4 tile[TILE];

    float xi = x[i * 3 + 0], yi = x[i * 3 + 1], zi = x[i * 3 + 2];
    float sqi = xi * xi + yi * yi + zi * zi;

    float bd[KNN];
    int bidx[KNN];
#pragma unroll
    for (int s = 0; s < KNN; ++s) { bd[s] = 3.0e38f; bidx[s] = 0x7fffffff; }
    float wd = 3.0e38f; int wi = 0x7fffffff; int wslot = 0;

    for (int base = split * csz; base < (split + 1) * csz; base += TILE) {
        __syncthreads();
#pragma unroll
        for (int r = 0; r < TILE / 256; ++r) {
            int j = threadIdx.x + r * 256;
            float a = x[(size_t)(base + j) * 3 + 0];
            float b = x[(size_t)(base + j) * 3 + 1];
            float c = x[(size_t)(base + j) * 3 + 2];
            tile[j] = make_float4(a, b, c, a * a + b * b + c * c);
        }
        __syncthreads();
#pragma unroll 4
        for (int j = 0; j < TILE; ++j) {
            float4 p = tile[j];
            float dot = xi * p.x + yi * p.y + zi * p.z;
            float d = sqi + p.w - 2.0f * dot;
            d = fmaxf(d, 0.0f);
            int jg = base + j;
            if (jg != i && (d < wd || (d == wd && jg < wi))) {
#pragma unroll
                for (int s = 0; s < KNN; ++s)
                    if (s == wslot) { bd[s] = d; bidx[s] = jg; }
                wd = bd[0]; wi = bidx[0]; wslot = 0;
#pragma unroll
                for (int s = 1; s < KNN; ++s) {
                    if (bd[s] > wd || (bd[s] == wd && bidx[s] > wi)) {
                        wd = bd[s]; wi = bidx[s]; wslot = s;
                    }
                }
            }
        }
    }
#pragma unroll
    for (int s = 0; s < KNN; ++s) {
        pd[(size_t)i * (NSPLIT * KNN) + split * KNN + s] = bd[s];
        pi[(size_t)i * (NSPLIT * KNN) + split * KNN + s] = bidx[s];
    }
}

// ---------------- kNN merge + rel_feat --------------------------------------
__global__ __launch_bounds__(256) void knn_merge_kernel(
    const float* __restrict__ x, int n, const float* __restrict__ pd,
    const int* __restrict__ pi, int* __restrict__ knn, float* __restrict__ relf)
{
    int i = blockIdx.x * 256 + threadIdx.x;
    float bd[KNN];
    int bidx[KNN];
#pragma unroll
    for (int s = 0; s < KNN; ++s) { bd[s] = 3.0e38f; bidx[s] = 0x7fffffff; }
    float wd = 3.0e38f; int wi = 0x7fffffff; int wslot = 0;

    for (int c = 0; c < NSPLIT * KNN; ++c) {
        float d = pd[(size_t)i * (NSPLIT * KNN) + c];
        int jg = pi[(size_t)i * (NSPLIT * KNN) + c];
        if (d < wd || (d == wd && jg < wi)) {
#pragma unroll
            for (int s = 0; s < KNN; ++s)
                if (s == wslot) { bd[s] = d; bidx[s] = jg; }
            wd = bd[0]; wi = bidx[0]; wslot = 0;
#pragma unroll
            for (int s = 1; s < KNN; ++s) {
                if (bd[s] > wd || (bd[s] == wd && bidx[s] > wi)) {
                    wd = bd[s]; wi = bidx[s]; wslot = s;
                }
            }
        }
    }

    float xi = x[i * 3 + 0], yi = x[i * 3 + 1], zi = x[i * 3 + 2];
    float rx[KNN], ry[KNN], rz[KNN];
    float sx = 0.f, sy = 0.f, sz = 0.f;
#pragma unroll
    for (int s = 0; s < KNN; ++s) {
        int j = bidx[s];
        knn[(size_t)i * KNN + s] = j;
        rx[s] = x[(size_t)j * 3 + 0] - xi;
        ry[s] = x[(size_t)j * 3 + 1] - yi;
        rz[s] = x[(size_t)j * 3 + 2] - zi;
        sx += rx[s]; sy += ry[s]; sz += rz[s];
    }
    float mx = sx / 12.0f, my = sy / 12.0f, mz = sz / 12.0f;
    float vx = 0.f, vy = 0.f, vz = 0.f;
#pragma unroll
    for (int s = 0; s < KNN; ++s) {
        float dx = rx[s] - mx, dy = ry[s] - my, dz = rz[s] - mz;
        vx += dx * dx; vy += dy * dy; vz += dz * dz;
    }
    relf[(size_t)i * 6 + 0] = mx;
    relf[(size_t)i * 6 + 1] = my;
    relf[(size_t)i * 6 + 2] = mz;
    relf[(size_t)i * 6 + 3] = sqrtf(vx / 12.0f);
    relf[(size_t)i * 6 + 4] = sqrtf(vy / 12.0f);
    relf[(size_t)i * 6 + 5] = sqrtf(vz / 12.0f);
}

// ---------------- Fourier positional encoding -------------------------------
__global__ __launch_bounds__(256) void pe_kernel(
    const float* __restrict__ x, const float* __restrict__ B0,
    const float* __restrict__ B1, const float* __restrict__ B2,
    float* __restrict__ pe, int n)
{
    int i = blockIdx.x * 256 + threadIdx.x;
    float x0 = x[i * 3 + 0], x1 = x[i * 3 + 1], x2 = x[i * 3 + 2];
    const float* Bm[3] = {B0, B1, B2};
#pragma unroll
    for (int m = 0; m < 3; ++m) {
        const float* B = Bm[m];
#pragma unroll
        for (int k = 0; k < 8; ++k) {
            float arg = x0 * B[k] + x1 * B[8 + k] + x2 * B[16 + k];
            pe[(size_t)i * 51 + m * 16 + k]     = sinf(arg);
            pe[(size_t)i * 51 + m * 16 + 8 + k] = cosf(arg);
        }
    }
    pe[(size_t)i * 51 + 48] = x0;
    pe[(size_t)i * 51 + 49] = x1;
    pe[(size_t)i * 51 + 50] = x2;
}

// ---------------- tiled fp32 GEMM + silu (+FiLM) -----------------------------
// C(n,192) = A(n,K) @ W(K,192); LAYER: A is piecewise [h | agg | relf], FiLM on.
template <bool LAYER>
__global__ __launch_bounds__(256) void gemm_silu_kernel(
    const float* __restrict__ A,
    const float* __restrict__ h, const float* __restrict__ agg, const float* __restrict__ relf,
    const float* __restrict__ W, const float* __restrict__ bias,
    const float* __restrict__ gamma, const float* __restrict__ beta,
    float* __restrict__ out, int n)
{
    __shared__ float As[16][68];  // [k][m], pad 68 -> write banks 8 distinct, 2-way (free)
    __shared__ float Bs[16][64];  // [k][c]
    const int tid = threadIdx.x;
    const int ty = tid >> 4, tx = tid & 15;
    const int m0 = blockIdx.x * 64;
    const int n0 = blockIdx.y * 64;
    const int K    = LAYER ? 390 : 51;
    const int Kpad = LAYER ? 400 : 64;

    float acc[4][4] = {};

    for (int k0 = 0; k0 < Kpad; k0 += 16) {
#pragma unroll
        for (int r = 0; r < 4; ++r) {
            int e = tid + r * 256;
            // A element
            int row = e >> 4, kk = e & 15;
            int gk = k0 + kk;
            int gi = m0 + row;
            float v = 0.0f;
            if (LAYER) {
                if (gk < 192)      v = h[(size_t)gi * 192 + gk];
                else if (gk < 384) v = agg[(size_t)gi * 192 + (gk - 192)];
                else if (gk < 390) v = relf[(size_t)gi * 6 + (gk - 384)];
            } else {
                if (gk < 51) v = A[(size_t)gi * 51 + gk];
            }
            As[kk][row] = v;
            // B element
            int c = e & 63, k2 = e >> 6;
            int gk2 = k0 + k2;
            Bs[k2][c] = (gk2 < K) ? W[(size_t)gk2 * 192 + n0 + c] : 0.0f;
        }
        __syncthreads();
#pragma unroll
        for (int k = 0; k < 16; ++k) {
            float4 av = *reinterpret_cast<const float4*>(&As[k][ty * 4]);
            float4 bv = *reinterpret_cast<const float4*>(&Bs[k][tx * 4]);
            float am[4] = {av.x, av.y, av.z, av.w};
            float bm[4] = {bv.x, bv.y, bv.z, bv.w};
#pragma unroll
            for (int a = 0; a < 4; ++a)
#pragma unroll
                for (int b = 0; b < 4; ++b)
                    acc[a][b] = fmaf(am[a], bm[b], acc[a][b]);
        }
        __syncthreads();
    }

#pragma unroll
    for (int a = 0; a < 4; ++a) {
        int gi = m0 + ty * 4 + a;
        float res[4];
#pragma unroll
        for (int b = 0; b < 4; ++b) {
            int gc = n0 + tx * 4 + b;
            float v = acc[a][b] + bias[gc];
            float s = 1.0f / (1.0f + expf(-v));
            v = v * s;                       // silu
            if (LAYER) v = v * gamma[gc] + beta[gc];  // FiLM
            res[b] = v;
        }
        *reinterpret_cast<float4*>(&out[(size_t)gi * 192 + n0 + tx * 4]) =
            make_float4(res[0], res[1], res[2], res[3]);
    }
}

// ---------------- neighbor aggregation (mean over 12 gathered rows) ----------
__global__ __launch_bounds__(256) void agg_kernel(
    const float* __restrict__ h, const int* __restrict__ knn,
    float* __restrict__ agg, int n)
{
    int flat = blockIdx.x * 256 + threadIdx.x;
    int i = flat / WIDTH;
    int c = flat - i * WIDTH;
    const int* kn = knn + (size_t)i * KNN;
    float s = 0.f;
#pragma unroll
    for (int j = 0; j < KNN; ++j) s += h[(size_t)kn[j] * WIDTH + c];
    agg[flat] = s / 12.0f;
}

// ---------------- output head ------------------------------------------------
__global__ __launch_bounds__(256) void out_kernel(
    const float* __restrict__ h, const float* __restrict__ Wout,
    const float* __restrict__ bout, float* __restrict__ out, int n)
{
    __shared__ float w[576];
    int t = threadIdx.x;
    for (int e = t; e < 576; e += 256) w[e] = Wout[e];
    __syncthreads();
    int i = blockIdx.x * 256 + t;
    float a0 = 0.f, a1 = 0.f, a2 = 0.f;
    for (int k = 0; k < 192; ++k) {
        float hv = h[(size_t)i * 192 + k];
        a0 = fmaf(hv, w[k * 3 + 0], a0);
        a1 = fmaf(hv, w[k * 3 + 1], a1);
        a2 = fmaf(hv, w[k * 3 + 2], a2);
    }
    out[(size_t)i * 3 + 0] = (a0 + bout[0]) * 0.01f;
    out[(size_t)i * 3 + 1] = (a1 + bout[1]) * 0.01f;
    out[(size_t)i * 3 + 2] = (a2 + bout[2]) * 0.01f;
}

// ---------------- launch ------------------------------------------------------
extern "C" void kernel_launch(void* const* d_in, const int* in_sizes, int n_in,
                              void* d_out, int out_size, void* d_ws, size_t ws_size,
                              hipStream_t stream)
{
    const float* x    = (const float*)d_in[0];
    const float* z    = (const float*)d_in[1];
    const float* B0   = (const float*)d_in[2];
    const float* B1   = (const float*)d_in[3];
    const float* B2   = (const float*)d_in[4];
    const float* Wp   = (const float*)d_in[5];
    const float* bp   = (const float*)d_in[6];
    const float* Wl   = (const float*)d_in[7];
    const float* bl   = (const float*)d_in[8];
    const float* Wg   = (const float*)d_in[9];
    const float* bg   = (const float*)d_in[10];
    const float* Wb   = (const float*)d_in[11];
    const float* bb   = (const float*)d_in[12];
    const float* Wout = (const float*)d_in[13];
    const float* bout = (const float*)d_in[14];

    int n = in_sizes[0] / 3;  // 32768

    // workspace layout (floats); partial-knn buffers alias hA/hB, pe aliases agg
    float* ws = (float*)d_ws;
    float* bias0  = ws;                  // 192
    float* gammaB = ws + 192;            // 768
    float* betaB  = ws + 192 + 768;      // 768
    size_t off = 192 + 768 + 768;        // 1728
    int*   knn  = (int*)(ws + off);      off += (size_t)n * KNN;
    float* relf = ws + off;              off += (size_t)n * 6;
    float* hA   = ws + off;              off += (size_t)n * WIDTH;
    float* hB   = ws + off;              off += (size_t)n * WIDTH;
    float* aggb = ws + off;              off += (size_t)n * WIDTH;
    float* pd = hA;           // n*96 floats  (fits in n*192)
    int*   pi = (int*)hB;     // n*96 ints
    float* pe = aggb;         // n*51 floats

    precompute_kernel<<<1, 256, 0, stream>>>(z, Wp, bp, Wg, bg, Wb, bb,
                                             bias0, gammaB, betaB);

    knn_partial_kernel<<<dim3(n / 256, NSPLIT), 256, 0, stream>>>(x, n, pd, pi);
    knn_merge_kernel<<<n / 256, 256, 0, stream>>>(x, n, pd, pi, knn, relf);

    pe_kernel<<<n / 256, 256, 0, stream>>>(x, B0, B1, B2, pe, n);

    // h0 = silu(pe @ Wp[:51] + bias0)   -> hA
    gemm_silu_kernel<false><<<dim3(n / 64, 3), 256, 0, stream>>>(
        pe, nullptr, nullptr, nullptr, Wp, bias0, nullptr, nullptr, hA, n);

    float* hcur = hA;
    float* hnxt = hB;
    for (int li = 0; li < 4; ++li) {
        agg_kernel<<<(size_t)n * WIDTH / 256, 256, 0, stream>>>(hcur, knn, aggb, n);
        gemm_silu_kernel<true><<<dim3(n / 64, 3), 256, 0, stream>>>(
            nullptr, hcur, aggb, relf,
            Wl + (size_t)li * 390 * 192, bl + (size_t)li * 192,
            gammaB + (size_t)li * 192, betaB + (size_t)li * 192, hnxt, n);
        float* t = hcur; hcur = hnxt; hnxt = t;
    }

    out_kernel<<<n / 256, 256, 0, stream>>>(hcur, Wout, bout, (float*)d_out, n);
}

// Round 2
// 1990.198 us; speedup vs baseline: 1.5099x; 1.5099x over previous
//
#include <hip/hip_runtime.h>
#include <math.h>

#define WIDTH 192
#define KNN 12
#define NSPLIT 2

// ---------- sorted-12 list of (d,idx) packed as positive doubles ----------
// key = __hiloint2double(float_bits(d), idx). For d >= 0 finite, u64 order
// == double order (positive, never NaN: exponent field never all-ones since
// d < FLT_MAX). Sorted ascending b0..b11; b11 = worst.
#define CE(a, b) { double _lo = fmin(a, b); double _hi = fmax(a, b); a = _lo; b = _hi; }
#define INSERT12(key) { \
    b11 = fmin(b11, key); \
    CE(b10, b11); CE(b9, b10); CE(b8, b9); CE(b7, b8); CE(b6, b7); \
    CE(b5, b6);  CE(b4, b5); CE(b3, b4); CE(b2, b3); CE(b1, b2); CE(b0, b1); }
#define DECL12 double b0,b1,b2,b3,b4,b5,b6,b7,b8,b9,b10,b11
#define INIT12 { b0=__hiloint2double(0x7F7FFFFF,0);  b1=__hiloint2double(0x7F7FFFFF,1); \
    b2=__hiloint2double(0x7F7FFFFF,2);  b3=__hiloint2double(0x7F7FFFFF,3); \
    b4=__hiloint2double(0x7F7FFFFF,4);  b5=__hiloint2double(0x7F7FFFFF,5); \
    b6=__hiloint2double(0x7F7FFFFF,6);  b7=__hiloint2double(0x7F7FFFFF,7); \
    b8=__hiloint2double(0x7F7FFFFF,8);  b9=__hiloint2double(0x7F7FFFFF,9); \
    b10=__hiloint2double(0x7F7FFFFF,10); b11=__hiloint2double(0x7F7FFFFF,11); }

// ---------------- prep: xw = (x,y,z,|x|^2) and padded Fourier PE -------------
__global__ __launch_bounds__(256) void prep_kernel(
    const float* __restrict__ x, const float* __restrict__ B0,
    const float* __restrict__ B1, const float* __restrict__ B2,
    float4* __restrict__ xw, float* __restrict__ pe, int n)
{
    int i = blockIdx.x * 256 + threadIdx.x;
    float x0 = x[i * 3 + 0], x1 = x[i * 3 + 1], x2 = x[i * 3 + 2];
    float sq = fmaf(x2, x2, fmaf(x1, x1, x0 * x0));
    xw[i] = make_float4(x0, x1, x2, sq);

    const float* Bm[3] = {B0, B1, B2};
    float* pr = pe + (size_t)i * 64;
#pragma unroll
    for (int m = 0; m < 3; ++m) {
        const float* B = Bm[m];
#pragma unroll
        for (int k = 0; k < 8; ++k) {
            float arg = x0 * B[k] + x1 * B[8 + k] + x2 * B[16 + k];
            pr[m * 16 + k]     = sinf(arg);
            pr[m * 16 + 8 + k] = cosf(arg);
        }
    }
    pr[48] = x0; pr[49] = x1; pr[50] = x2;
#pragma unroll
    for (int c = 51; c < 64; ++c) pr[c] = 0.0f;
}

// ---------------- precompute: fold z into biases -----------------------------
__global__ __launch_bounds__(256) void precompute_kernel(
    const float* __restrict__ z, const float* __restrict__ Wp, const float* __restrict__ bp,
    const float* __restrict__ Wg, const float* __restrict__ bg,
    const float* __restrict__ Wb, const float* __restrict__ bb,
    float* __restrict__ bias0, float* __restrict__ gammaB, float* __restrict__ betaB)
{
    __shared__ float zs[64];
    int t = threadIdx.x;
    if (t < 64) zs[t] = z[t];
    __syncthreads();
    if (t < WIDTH) {
        float acc = bp[t];
        for (int k = 0; k < 64; ++k) acc += zs[k] * Wp[(51 + k) * WIDTH + t];
        bias0[t] = acc;
        for (int l = 0; l < 4; ++l) {
            float g = bg[l * WIDTH + t];
            float b = bb[l * WIDTH + t];
            for (int k = 0; k < 64; ++k) {
                g += zs[k] * Wg[(l * 64 + k) * WIDTH + t];
                b += zs[k] * Wb[(l * 64 + k) * WIDTH + t];
            }
            gammaB[l * WIDTH + t] = g;
            betaB[l * WIDTH + t] = b;
        }
    }
}

// ---------------- kNN: sorted-12 f64 keys, NSPLIT candidate splits -----------
__global__ __launch_bounds__(256) void knn_kernel(
    const float4* __restrict__ xw, int n, double* __restrict__ pd)
{
    int i = blockIdx.x * 256 + threadIdx.x;
    int split = blockIdx.y;
    int csz = n / NSPLIT;
    int jstart = split * csz, jend = jstart + csz;

    float4 q = xw[i];
    float xi = q.x, yi = q.y, zi = q.z, sqi = q.w;

    DECL12; INIT12;
    float worst = 3.402823466e+38f;

    for (int j0 = jstart; j0 < jend; j0 += 8) {
        float4 c[8];
#pragma unroll
        for (int r = 0; r < 8; ++r) c[r] = xw[j0 + r];
#pragma unroll
        for (int r = 0; r < 8; ++r) {
            int jg = j0 + r;
            float dot = fmaf(zi, c[r].z, fmaf(yi, c[r].y, xi * c[r].x));
            float d = fmaf(-2.0f, dot, sqi + c[r].w);
            d = fmaxf(d, 0.0f);
            if (d <= worst && jg != i) {
                double key = __hiloint2double(__float_as_int(d), jg);
                INSERT12(key);
                worst = __int_as_float(__double2hiint(b11));
            }
        }
    }
    double* out = pd + ((size_t)i * NSPLIT + split) * 12;
    out[0]=b0; out[1]=b1; out[2]=b2; out[3]=b3; out[4]=b4; out[5]=b5;
    out[6]=b6; out[7]=b7; out[8]=b8; out[9]=b9; out[10]=b10; out[11]=b11;
}

// ---------------- merge splits + rel_feat (padded to 8) ----------------------
__global__ __launch_bounds__(256) void knn_merge_kernel(
    const float* __restrict__ x, int n, const double* __restrict__ pd,
    unsigned short* __restrict__ knn, float* __restrict__ relf)
{
    int i = blockIdx.x * 256 + threadIdx.x;
    DECL12; INIT12;
    const double* src = pd + (size_t)i * (NSPLIT * 12);
#pragma unroll
    for (int c = 0; c < NSPLIT * 12; ++c) {
        double key = src[c];
        INSERT12(key);
    }
    int idx[KNN];
    idx[0]=__double2loint(b0);  idx[1]=__double2loint(b1);  idx[2]=__double2loint(b2);
    idx[3]=__double2loint(b3);  idx[4]=__double2loint(b4);  idx[5]=__double2loint(b5);
    idx[6]=__double2loint(b6);  idx[7]=__double2loint(b7);  idx[8]=__double2loint(b8);
    idx[9]=__double2loint(b9);  idx[10]=__double2loint(b10); idx[11]=__double2loint(b11);

    float xi = x[i * 3 + 0], yi = x[i * 3 + 1], zi = x[i * 3 + 2];
    float rx[KNN], ry[KNN], rz[KNN];
    float sx = 0.f, sy = 0.f, sz = 0.f;
#pragma unroll
    for (int s = 0; s < KNN; ++s) {
        int j = idx[s];
        knn[(size_t)i * KNN + s] = (unsigned short)j;
        rx[s] = x[(size_t)j * 3 + 0] - xi;
        ry[s] = x[(size_t)j * 3 + 1] - yi;
        rz[s] = x[(size_t)j * 3 + 2] - zi;
        sx += rx[s]; sy += ry[s]; sz += rz[s];
    }
    float mx = sx / 12.0f, my = sy / 12.0f, mz = sz / 12.0f;
    float vx = 0.f, vy = 0.f, vz = 0.f;
#pragma unroll
    for (int s = 0; s < KNN; ++s) {
        float dx = rx[s] - mx, dy = ry[s] - my, dz = rz[s] - mz;
        vx += dx * dx; vy += dy * dy; vz += dz * dz;
    }
    float* rr = relf + (size_t)i * 8;
    rr[0] = mx; rr[1] = my; rr[2] = mz;
    rr[3] = sqrtf(vx / 12.0f); rr[4] = sqrtf(vy / 12.0f); rr[5] = sqrtf(vz / 12.0f);
    rr[6] = 0.0f; rr[7] = 0.0f;
}

// ---------------- GEMM + silu (+FiLM): 128x192 tile, 8x12 micro --------------
// first layer (!LAYER): A = pe (n x 64 padded), K=64 (zero-padded cols kill
// Wp rows 51..63). LAYER: A = [h (192) | agg (192) | relf8 (6+2 zeros)].
template <bool LAYER>
__global__ __launch_bounds__(256) void gemm_silu_kernel(
    const float* __restrict__ A0, const float* __restrict__ Agg,
    const float* __restrict__ Rel,
    const float* __restrict__ W, const float* __restrict__ bias,
    const float* __restrict__ gamma, const float* __restrict__ beta,
    float* __restrict__ out)
{
    __shared__ float As[16][132];   // [k][row], padded for 16B-aligned f4 reads
    __shared__ float Bs[16][196];   // [k][col]
    const int tid = threadIdx.x;
    const int ty = tid >> 4, tx = tid & 15;   // ty: row group (8), tx: col group (12)
    const int m0 = blockIdx.x * 128;

    float acc[8][12] = {};

    const int NCH = LAYER ? 24 : 4;   // full 16-wide K chunks
    for (int ch = 0; ch < NCH; ++ch) {
        const int k0 = ch * 16;
        // stage A: 128 rows x 16 k; thread loads 8 consecutive k of one row
        {
            int row = tid >> 1, koff = (tid & 1) * 8;
            int gi = m0 + row;
            const float* src; int stride, col;
            if (!LAYER)            { src = A0;  stride = 64;  col = k0 + koff; }
            else if (k0 < 192)     { src = A0;  stride = 192; col = k0 + koff; }
            else                   { src = Agg; stride = 192; col = k0 - 192 + koff; }
            float4 v0 = *(const float4*)&src[(size_t)gi * stride + col];
            float4 v1 = *(const float4*)&src[(size_t)gi * stride + col + 4];
            As[koff + 0][row] = v0.x; As[koff + 1][row] = v0.y;
            As[koff + 2][row] = v0.z; As[koff + 3][row] = v0.w;
            As[koff + 4][row] = v1.x; As[koff + 5][row] = v1.y;
            As[koff + 6][row] = v1.z; As[koff + 7][row] = v1.w;
        }
        // stage B: 16 k x 192 cols; thread loads 12 cols of one k
        {
            int k2 = tid >> 4, c = (tid & 15) * 12;
            const float* wr = &W[(size_t)(k0 + k2) * 192 + c];
            float4 w0 = *(const float4*)&wr[0];
            float4 w1 = *(const float4*)&wr[4];
            float4 w2 = *(const float4*)&wr[8];
            *(float4*)&Bs[k2][c + 0] = w0;
            *(float4*)&Bs[k2][c + 4] = w1;
            *(float4*)&Bs[k2][c + 8] = w2;
        }
        __syncthreads();
#pragma unroll
        for (int k = 0; k < 16; ++k) {
            float4 a0 = *(const float4*)&As[k][ty * 8 + 0];
            float4 a1 = *(const float4*)&As[k][ty * 8 + 4];
            float av[8] = {a0.x, a0.y, a0.z, a0.w, a1.x, a1.y, a1.z, a1.w};
            float4 q0 = *(const float4*)&Bs[k][tx * 12 + 0];
            float4 q1 = *(const float4*)&Bs[k][tx * 12 + 4];
            float4 q2 = *(const float4*)&Bs[k][tx * 12 + 8];
            float bv[12] = {q0.x, q0.y, q0.z, q0.w, q1.x, q1.y, q1.z, q1.w,
                            q2.x, q2.y, q2.z, q2.w};
#pragma unroll
            for (int a = 0; a < 8; ++a)
#pragma unroll
                for (int b = 0; b < 12; ++b)
                    acc[a][b] = fmaf(av[a], bv[b], acc[a][b]);
        }
        __syncthreads();
    }

    if (LAYER) {  // tail chunk: k = 384..391 from relf8 (cols 6,7 are zero)
        {
            int row = tid >> 1, col = (tid & 1) * 4;
            float4 v = *(const float4*)&Rel[(size_t)(m0 + row) * 8 + col];
            As[col + 0][row] = v.x; As[col + 1][row] = v.y;
            As[col + 2][row] = v.z; As[col + 3][row] = v.w;
        }
        {
            int k2 = tid >> 4, c = (tid & 15) * 12;
            if (k2 < 8) {
                int gk = 384 + k2; if (gk > 389) gk = 389;  // clamp: A rows 6,7 = 0
                const float* wr = &W[(size_t)gk * 192 + c];
                float4 w0 = *(const float4*)&wr[0];
                float4 w1 = *(const float4*)&wr[4];
                float4 w2 = *(const float4*)&wr[8];
                *(float4*)&Bs[k2][c + 0] = w0;
                *(float4*)&Bs[k2][c + 4] = w1;
                *(float4*)&Bs[k2][c + 8] = w2;
            }
        }
        __syncthreads();
#pragma unroll
        for (int k = 0; k < 8; ++k) {
            float4 a0 = *(const float4*)&As[k][ty * 8 + 0];
            float4 a1 = *(const float4*)&As[k][ty * 8 + 4];
            float av[8] = {a0.x, a0.y, a0.z, a0.w, a1.x, a1.y, a1.z, a1.w};
            float4 q0 = *(const float4*)&Bs[k][tx * 12 + 0];
            float4 q1 = *(const float4*)&Bs[k][tx * 12 + 4];
            float4 q2 = *(const float4*)&Bs[k][tx * 12 + 8];
            float bv[12] = {q0.x, q0.y, q0.z, q0.w, q1.x, q1.y, q1.z, q1.w,
                            q2.x, q2.y, q2.z, q2.w};
#pragma unroll
            for (int a = 0; a < 8; ++a)
#pragma unroll
                for (int b = 0; b < 12; ++b)
                    acc[a][b] = fmaf(av[a], bv[b], acc[a][b]);
        }
        __syncthreads();
    }

    // epilogue
#pragma unroll
    for (int a = 0; a < 8; ++a) {
        int gi = m0 + ty * 8 + a;
        float res[12];
#pragma unroll
        for (int b = 0; b < 12; ++b) {
            int gc = tx * 12 + b;
            float v = acc[a][b] + bias[gc];
            float s = 1.0f / (1.0f + expf(-v));
            v = v * s;
            if (LAYER) v = v * gamma[gc] + beta[gc];
            res[b] = v;
        }
        float* orow = &out[(size_t)gi * 192 + tx * 12];
        *(float4*)&orow[0] = make_float4(res[0], res[1], res[2], res[3]);
        *(float4*)&orow[4] = make_float4(res[4], res[5], res[6], res[7]);
        *(float4*)&orow[8] = make_float4(res[8], res[9], res[10], res[11]);
    }
}

// ---------------- neighbor aggregation (float4) ------------------------------
__global__ __launch_bounds__(256) void agg_kernel(
    const float4* __restrict__ h4, const unsigned short* __restrict__ knn,
    float4* __restrict__ agg4, int n)
{
    int flat = blockIdx.x * 256 + threadIdx.x;  // n*48 threads
    int i = flat / 48;
    int c4 = flat - i * 48;
    const unsigned short* kn = knn + (size_t)i * KNN;
    float4 s = make_float4(0.f, 0.f, 0.f, 0.f);
#pragma unroll
    for (int j = 0; j < KNN; ++j) {
        float4 v = h4[(size_t)kn[j] * 48 + c4];
        s.x += v.x; s.y += v.y; s.z += v.z; s.w += v.w;
    }
    const float r = 1.0f / 12.0f;
    agg4[flat] = make_float4(s.x * r, s.y * r, s.z * r, s.w * r);
}

// ---------------- output head ------------------------------------------------
__global__ __launch_bounds__(256) void out_kernel(
    const float4* __restrict__ h4, const float* __restrict__ Wout,
    const float* __restrict__ bout, float* __restrict__ out, int n)
{
    __shared__ float w[576];
    int t = threadIdx.x;
    for (int e = t; e < 576; e += 256) w[e] = Wout[e];
    __syncthreads();
    int i = blockIdx.x * 256 + t;
    float a0 = 0.f, a1 = 0.f, a2 = 0.f;
    for (int k4 = 0; k4 < 48; ++k4) {
        float4 hv = h4[(size_t)i * 48 + k4];
        int k = k4 * 4;
        a0 = fmaf(hv.x, w[k * 3 + 0], a0); a1 = fmaf(hv.x, w[k * 3 + 1], a1); a2 = fmaf(hv.x, w[k * 3 + 2], a2);
        a0 = fmaf(hv.y, w[k * 3 + 3], a0); a1 = fmaf(hv.y, w[k * 3 + 4], a1); a2 = fmaf(hv.y, w[k * 3 + 5], a2);
        a0 = fmaf(hv.z, w[k * 3 + 6], a0); a1 = fmaf(hv.z, w[k * 3 + 7], a1); a2 = fmaf(hv.z, w[k * 3 + 8], a2);
        a0 = fmaf(hv.w, w[k * 3 + 9], a0); a1 = fmaf(hv.w, w[k * 3 + 10], a1); a2 = fmaf(hv.w, w[k * 3 + 11], a2);
    }
    out[(size_t)i * 3 + 0] = (a0 + bout[0]) * 0.01f;
    out[(size_t)i * 3 + 1] = (a1 + bout[1]) * 0.01f;
    out[(size_t)i * 3 + 2] = (a2 + bout[2]) * 0.01f;
}

// ---------------- launch ------------------------------------------------------
extern "C" void kernel_launch(void* const* d_in, const int* in_sizes, int n_in,
                              void* d_out, int out_size, void* d_ws, size_t ws_size,
                              hipStream_t stream)
{
    const float* x    = (const float*)d_in[0];
    const float* z    = (const float*)d_in[1];
    const float* B0   = (const float*)d_in[2];
    const float* B1   = (const float*)d_in[3];
    const float* B2   = (const float*)d_in[4];
    const float* Wp   = (const float*)d_in[5];
    const float* bp   = (const float*)d_in[6];
    const float* Wl   = (const float*)d_in[7];
    const float* bl   = (const float*)d_in[8];
    const float* Wg   = (const float*)d_in[9];
    const float* bg   = (const float*)d_in[10];
    const float* Wb   = (const float*)d_in[11];
    const float* bb   = (const float*)d_in[12];
    const float* Wout = (const float*)d_in[13];
    const float* bout = (const float*)d_in[14];

    int n = in_sizes[0] / 3;  // 32768

    // workspace layout (float offsets); total = 590n + 1728 floats (~77.3 MB)
    float* ws = (float*)d_ws;
    float* bias0  = ws;                    // 192
    float* gammaB = ws + 192;              // 768
    float* betaB  = ws + 960;              // 768
    size_t off = 1728;
    unsigned short* knn = (unsigned short*)(ws + off);  off += (size_t)n * 6;  // 12n u16
    float* relf = ws + off;                off += (size_t)n * 8;
    float* hA   = ws + off;                off += (size_t)n * 192;
    float* hB   = ws + off;                off += (size_t)n * 192;
    float* aggb = ws + off;                off += (size_t)n * 192;
    // aliases (lifetimes disjoint):
    double* pd  = (double*)hA;             // n*24 doubles, dead before gemm0 writes hA
    float*  pe  = hB;                      // n*64, dead after gemm0 reads it
    float4* xw  = (float4*)aggb;           // n float4, dead before first agg write

    prep_kernel<<<n / 256, 256, 0, stream>>>(x, B0, B1, B2, xw, pe, n);
    precompute_kernel<<<1, 256, 0, stream>>>(z, Wp, bp, Wg, bg, Wb, bb,
                                             bias0, gammaB, betaB);

    knn_kernel<<<dim3(n / 256, NSPLIT), 256, 0, stream>>>(xw, n, pd);
    knn_merge_kernel<<<n / 256, 256, 0, stream>>>(x, n, pd, knn, relf);

    // h0 = silu(pe @ Wp[:64] + bias0) -> hA   (pe cols 51..63 are zero)
    gemm_silu_kernel<false><<<n / 128, 256, 0, stream>>>(
        pe, nullptr, nullptr, Wp, bias0, nullptr, nullptr, hA);

    float* hcur = hA;
    float* hnxt = hB;
    for (int li = 0; li < 4; ++li) {
        agg_kernel<<<(size_t)n * 48 / 256, 256, 0, stream>>>(
            (const float4*)hcur, knn, (float4*)aggb, n);
        gemm_silu_kernel<true><<<n / 128, 256, 0, stream>>>(
            hcur, aggb, relf,
            Wl + (size_t)li * 390 * 192, bl + (size_t)li * 192,
            gammaB + (size_t)li * 192, betaB + (size_t)li * 192, hnxt);
        float* t = hcur; hcur = hnxt; hnxt = t;
    }

    out_kernel<<<n / 256, 256, 0, stream>>>((const float4*)hcur, Wout, bout,
                                            (float*)d_out, n);
}

// Round 3
// 1390.961 us; speedup vs baseline: 2.1604x; 1.4308x over previous
//
#include <hip/hip_runtime.h>
#include <math.h>

#define WIDTH 192
#define KNN 12
#define NSPLIT 4

// ---------- sorted-12 list of (d,idx) packed as positive doubles ----------
// key = __hiloint2double(float_bits(d), idx). For d >= 0 finite, u64 order
// == double order (positive, never NaN: exponent field never all-ones since
// d < FLT_MAX). Sorted ascending b0..b11; b11 = worst.
#define CE(a, b) { double _lo = fmin(a, b); double _hi = fmax(a, b); a = _lo; b = _hi; }
#define INSERT12(key) { \
    b11 = fmin(b11, key); \
    CE(b10, b11); CE(b9, b10); CE(b8, b9); CE(b7, b8); CE(b6, b7); \
    CE(b5, b6);  CE(b4, b5); CE(b3, b4); CE(b2, b3); CE(b1, b2); CE(b0, b1); }
#define DECL12 double b0,b1,b2,b3,b4,b5,b6,b7,b8,b9,b10,b11
#define INIT12 { b0=__hiloint2double(0x7F7FFFFF,0);  b1=__hiloint2double(0x7F7FFFFF,1); \
    b2=__hiloint2double(0x7F7FFFFF,2);  b3=__hiloint2double(0x7F7FFFFF,3); \
    b4=__hiloint2double(0x7F7FFFFF,4);  b5=__hiloint2double(0x7F7FFFFF,5); \
    b6=__hiloint2double(0x7F7FFFFF,6);  b7=__hiloint2double(0x7F7FFFFF,7); \
    b8=__hiloint2double(0x7F7FFFFF,8);  b9=__hiloint2double(0x7F7FFFFF,9); \
    b10=__hiloint2double(0x7F7FFFFF,10); b11=__hiloint2double(0x7F7FFFFF,11); }

// ---------------- prep: xw = (x,y,z,|x|^2) and padded Fourier PE -------------
__global__ __launch_bounds__(256) void prep_kernel(
    const float* __restrict__ x, const float* __restrict__ B0,
    const float* __restrict__ B1, const float* __restrict__ B2,
    float4* __restrict__ xw, float* __restrict__ pe, int n)
{
    int i = blockIdx.x * 256 + threadIdx.x;
    float x0 = x[i * 3 + 0], x1 = x[i * 3 + 1], x2 = x[i * 3 + 2];
    float sq = fmaf(x2, x2, fmaf(x1, x1, x0 * x0));
    xw[i] = make_float4(x0, x1, x2, sq);

    const float* Bm[3] = {B0, B1, B2};
    float* pr = pe + (size_t)i * 64;
#pragma unroll
    for (int m = 0; m < 3; ++m) {
        const float* B = Bm[m];
#pragma unroll
        for (int k = 0; k < 8; ++k) {
            float arg = x0 * B[k] + x1 * B[8 + k] + x2 * B[16 + k];
            pr[m * 16 + k]     = sinf(arg);
            pr[m * 16 + 8 + k] = cosf(arg);
        }
    }
    pr[48] = x0; pr[49] = x1; pr[50] = x2;
#pragma unroll
    for (int c = 51; c < 64; ++c) pr[c] = 0.0f;
}

// ---------------- precompute: fold z into biases -----------------------------
__global__ __launch_bounds__(256) void precompute_kernel(
    const float* __restrict__ z, const float* __restrict__ Wp, const float* __restrict__ bp,
    const float* __restrict__ Wg, const float* __restrict__ bg,
    const float* __restrict__ Wb, const float* __restrict__ bb,
    float* __restrict__ bias0, float* __restrict__ gammaB, float* __restrict__ betaB)
{
    __shared__ float zs[64];
    int t = threadIdx.x;
    if (t < 64) zs[t] = z[t];
    __syncthreads();
    if (t < WIDTH) {
        float acc = bp[t];
        for (int k = 0; k < 64; ++k) acc += zs[k] * Wp[(51 + k) * WIDTH + t];
        bias0[t] = acc;
        for (int l = 0; l < 4; ++l) {
            float g = bg[l * WIDTH + t];
            float b = bb[l * WIDTH + t];
            for (int k = 0; k < 64; ++k) {
                g += zs[k] * Wg[(l * 64 + k) * WIDTH + t];
                b += zs[k] * Wb[(l * 64 + k) * WIDTH + t];
            }
            gammaB[l * WIDTH + t] = g;
            betaB[l * WIDTH + t] = b;
        }
    }
}

// ---------------- kNN: sorted-12 f64 keys, register-prefetched candidates ----
__global__ __launch_bounds__(256) void knn_kernel(
    const float4* __restrict__ xw, int n, double* __restrict__ pd)
{
    int i = blockIdx.x * 256 + threadIdx.x;
    int split = blockIdx.y;
    int csz = n / NSPLIT;
    int jstart = split * csz, jend = jstart + csz;

    float4 q = xw[i];
    float xi = q.x, yi = q.y, zi = q.z, sqi = q.w;

    DECL12; INIT12;
    float worst = 3.402823466e+38f;

    float4 cur[8], nxt[8];
#pragma unroll
    for (int r = 0; r < 8; ++r) cur[r] = xw[jstart + r];

    for (int j0 = jstart; j0 < jend; j0 += 8) {
        int jp = j0 + 8;
        if (jp >= jend) jp = jstart;      // wrap: harmless dummy prefetch
#pragma unroll
        for (int r = 0; r < 8; ++r) nxt[r] = xw[jp + r];
#pragma unroll
        for (int r = 0; r < 8; ++r) {
            int jg = j0 + r;
            float dot = fmaf(zi, cur[r].z, fmaf(yi, cur[r].y, xi * cur[r].x));
            float d = fmaf(-2.0f, dot, sqi + cur[r].w);
            // raw d may be < 0 only when true dist ~ 0, which always passes
            if (d <= worst && jg != i) {
                d = fmaxf(d, 0.0f);
                double key = __hiloint2double(__float_as_int(d), jg);
                INSERT12(key);
                worst = __int_as_float(__double2hiint(b11));
            }
        }
#pragma unroll
        for (int r = 0; r < 8; ++r) cur[r] = nxt[r];
    }
    double* out = pd + ((size_t)i * NSPLIT + split) * 12;
    out[0]=b0; out[1]=b1; out[2]=b2; out[3]=b3; out[4]=b4; out[5]=b5;
    out[6]=b6; out[7]=b7; out[8]=b8; out[9]=b9; out[10]=b10; out[11]=b11;
}

// ---------------- merge splits + rel_feat (padded to 8) ----------------------
__global__ __launch_bounds__(256) void knn_merge_kernel(
    const float* __restrict__ x, int n, const double* __restrict__ pd,
    unsigned short* __restrict__ knn, float* __restrict__ relf)
{
    int i = blockIdx.x * 256 + threadIdx.x;
    DECL12; INIT12;
    const double* src = pd + (size_t)i * (NSPLIT * 12);
#pragma unroll
    for (int c = 0; c < NSPLIT * 12; ++c) {
        double key = src[c];
        INSERT12(key);
    }
    int idx[KNN];
    idx[0]=__double2loint(b0);  idx[1]=__double2loint(b1);  idx[2]=__double2loint(b2);
    idx[3]=__double2loint(b3);  idx[4]=__double2loint(b4);  idx[5]=__double2loint(b5);
    idx[6]=__double2loint(b6);  idx[7]=__double2loint(b7);  idx[8]=__double2loint(b8);
    idx[9]=__double2loint(b9);  idx[10]=__double2loint(b10); idx[11]=__double2loint(b11);

    float xi = x[i * 3 + 0], yi = x[i * 3 + 1], zi = x[i * 3 + 2];
    float rx[KNN], ry[KNN], rz[KNN];
    float sx = 0.f, sy = 0.f, sz = 0.f;
#pragma unroll
    for (int s = 0; s < KNN; ++s) {
        int j = idx[s];
        knn[(size_t)i * KNN + s] = (unsigned short)j;
        rx[s] = x[(size_t)j * 3 + 0] - xi;
        ry[s] = x[(size_t)j * 3 + 1] - yi;
        rz[s] = x[(size_t)j * 3 + 2] - zi;
        sx += rx[s]; sy += ry[s]; sz += rz[s];
    }
    float mx = sx / 12.0f, my = sy / 12.0f, mz = sz / 12.0f;
    float vx = 0.f, vy = 0.f, vz = 0.f;
#pragma unroll
    for (int s = 0; s < KNN; ++s) {
        float dx = rx[s] - mx, dy = ry[s] - my, dz = rz[s] - mz;
        vx += dx * dx; vy += dy * dy; vz += dz * dz;
    }
    float* rr = relf + (size_t)i * 8;
    rr[0] = mx; rr[1] = my; rr[2] = mz;
    rr[3] = sqrtf(vx / 12.0f); rr[4] = sqrtf(vy / 12.0f); rr[5] = sqrtf(vz / 12.0f);
    rr[6] = 0.0f; rr[7] = 0.0f;
}

// ---------------- GEMM + silu (+FiLM): 128x192 tile, 8x12 micro --------------
// first layer (!LAYER): A = pe (n x 64 padded), K=64 (zero-padded cols kill
// Wp rows 51..63). LAYER: A = [h (192) | agg (192) | relf8 (6+2 zeros)].
template <bool LAYER>
__global__ __launch_bounds__(256) void gemm_silu_kernel(
    const float* __restrict__ A0, const float* __restrict__ Agg,
    const float* __restrict__ Rel,
    const float* __restrict__ W, const float* __restrict__ bias,
    const float* __restrict__ gamma, const float* __restrict__ beta,
    float* __restrict__ out)
{
    __shared__ float As[16][132];   // [k][row], padded for 16B-aligned f4 reads
    __shared__ float Bs[16][196];   // [k][col]
    const int tid = threadIdx.x;
    const int ty = tid >> 4, tx = tid & 15;   // ty: row group (8), tx: col group (12)
    const int m0 = blockIdx.x * 128;

    float acc[8][12] = {};

    const int NCH = LAYER ? 24 : 4;   // full 16-wide K chunks
    for (int ch = 0; ch < NCH; ++ch) {
        const int k0 = ch * 16;
        // stage A: 128 rows x 16 k; thread loads 8 consecutive k of one row
        {
            int row = tid >> 1, koff = (tid & 1) * 8;
            int gi = m0 + row;
            const float* src; int stride, col;
            if (!LAYER)            { src = A0;  stride = 64;  col = k0 + koff; }
            else if (k0 < 192)     { src = A0;  stride = 192; col = k0 + koff; }
            else                   { src = Agg; stride = 192; col = k0 - 192 + koff; }
            float4 v0 = *(const float4*)&src[(size_t)gi * stride + col];
            float4 v1 = *(const float4*)&src[(size_t)gi * stride + col + 4];
            As[koff + 0][row] = v0.x; As[koff + 1][row] = v0.y;
            As[koff + 2][row] = v0.z; As[koff + 3][row] = v0.w;
            As[koff + 4][row] = v1.x; As[koff + 5][row] = v1.y;
            As[koff + 6][row] = v1.z; As[koff + 7][row] = v1.w;
        }
        // stage B: 16 k x 192 cols; thread loads 12 cols of one k
        {
            int k2 = tid >> 4, c = (tid & 15) * 12;
            const float* wr = &W[(size_t)(k0 + k2) * 192 + c];
            float4 w0 = *(const float4*)&wr[0];
            float4 w1 = *(const float4*)&wr[4];
            float4 w2 = *(const float4*)&wr[8];
            *(float4*)&Bs[k2][c + 0] = w0;
            *(float4*)&Bs[k2][c + 4] = w1;
            *(float4*)&Bs[k2][c + 8] = w2;
        }
        __syncthreads();
#pragma unroll
        for (int k = 0; k < 16; ++k) {
            float4 a0 = *(const float4*)&As[k][ty * 8 + 0];
            float4 a1 = *(const float4*)&As[k][ty * 8 + 4];
            float av[8] = {a0.x, a0.y, a0.z, a0.w, a1.x, a1.y, a1.z, a1.w};
            float4 q0 = *(const float4*)&Bs[k][tx * 12 + 0];
            float4 q1 = *(const float4*)&Bs[k][tx * 12 + 4];
            float4 q2 = *(const float4*)&Bs[k][tx * 12 + 8];
            float bv[12] = {q0.x, q0.y, q0.z, q0.w, q1.x, q1.y, q1.z, q1.w,
                            q2.x, q2.y, q2.z, q2.w};
#pragma unroll
            for (int a = 0; a < 8; ++a)
#pragma unroll
                for (int b = 0; b < 12; ++b)
                    acc[a][b] = fmaf(av[a], bv[b], acc[a][b]);
        }
        __syncthreads();
    }

    if (LAYER) {  // tail chunk: k = 384..391 from relf8 (cols 6,7 are zero)
        {
            int row = tid >> 1, col = (tid & 1) * 4;
            float4 v = *(const float4*)&Rel[(size_t)(m0 + row) * 8 + col];
            As[col + 0][row] = v.x; As[col + 1][row] = v.y;
            As[col + 2][row] = v.z; As[col + 3][row] = v.w;
        }
        {
            int k2 = tid >> 4, c = (tid & 15) * 12;
            if (k2 < 8) {
                int gk = 384 + k2; if (gk > 389) gk = 389;  // clamp: A rows 6,7 = 0
                const float* wr = &W[(size_t)gk * 192 + c];
                float4 w0 = *(const float4*)&wr[0];
                float4 w1 = *(const float4*)&wr[4];
                float4 w2 = *(const float4*)&wr[8];
                *(float4*)&Bs[k2][c + 0] = w0;
                *(float4*)&Bs[k2][c + 4] = w1;
                *(float4*)&Bs[k2][c + 8] = w2;
            }
        }
        __syncthreads();
#pragma unroll
        for (int k = 0; k < 8; ++k) {
            float4 a0 = *(const float4*)&As[k][ty * 8 + 0];
            float4 a1 = *(const float4*)&As[k][ty * 8 + 4];
            float av[8] = {a0.x, a0.y, a0.z, a0.w, a1.x, a1.y, a1.z, a1.w};
            float4 q0 = *(const float4*)&Bs[k][tx * 12 + 0];
            float4 q1 = *(const float4*)&Bs[k][tx * 12 + 4];
            float4 q2 = *(const float4*)&Bs[k][tx * 12 + 8];
            float bv[12] = {q0.x, q0.y, q0.z, q0.w, q1.x, q1.y, q1.z, q1.w,
                            q2.x, q2.y, q2.z, q2.w};
#pragma unroll
            for (int a = 0; a < 8; ++a)
#pragma unroll
                for (int b = 0; b < 12; ++b)
                    acc[a][b] = fmaf(av[a], bv[b], acc[a][b]);
        }
        __syncthreads();
    }

    // epilogue
#pragma unroll
    for (int a = 0; a < 8; ++a) {
        int gi = m0 + ty * 8 + a;
        float res[12];
#pragma unroll
        for (int b = 0; b < 12; ++b) {
            int gc = tx * 12 + b;
            float v = acc[a][b] + bias[gc];
            float s = 1.0f / (1.0f + expf(-v));
            v = v * s;
            if (LAYER) v = v * gamma[gc] + beta[gc];
            res[b] = v;
        }
        float* orow = &out[(size_t)gi * 192 + tx * 12];
        *(float4*)&orow[0] = make_float4(res[0], res[1], res[2], res[3]);
        *(float4*)&orow[4] = make_float4(res[4], res[5], res[6], res[7]);
        *(float4*)&orow[8] = make_float4(res[8], res[9], res[10], res[11]);
    }
}

// ---------------- neighbor aggregation (float4) ------------------------------
__global__ __launch_bounds__(256) void agg_kernel(
    const float4* __restrict__ h4, const unsigned short* __restrict__ knn,
    float4* __restrict__ agg4, int n)
{
    int flat = blockIdx.x * 256 + threadIdx.x;  // n*48 threads
    int i = flat / 48;
    int c4 = flat - i * 48;
    const unsigned short* kn = knn + (size_t)i * KNN;
    float4 s = make_float4(0.f, 0.f, 0.f, 0.f);
#pragma unroll
    for (int j = 0; j < KNN; ++j) {
        float4 v = h4[(size_t)kn[j] * 48 + c4];
        s.x += v.x; s.y += v.y; s.z += v.z; s.w += v.w;
    }
    const float r = 1.0f / 12.0f;
    agg4[flat] = make_float4(s.x * r, s.y * r, s.z * r, s.w * r);
}

// ---------------- output head ------------------------------------------------
__global__ __launch_bounds__(256) void out_kernel(
    const float4* __restrict__ h4, const float* __restrict__ Wout,
    const float* __restrict__ bout, float* __restrict__ out, int n)
{
    __shared__ float w[576];
    int t = threadIdx.x;
    for (int e = t; e < 576; e += 256) w[e] = Wout[e];
    __syncthreads();
    int i = blockIdx.x * 256 + t;
    float a0 = 0.f, a1 = 0.f, a2 = 0.f;
    for (int k4 = 0; k4 < 48; ++k4) {
        float4 hv = h4[(size_t)i * 48 + k4];
        int k = k4 * 4;
        a0 = fmaf(hv.x, w[k * 3 + 0], a0); a1 = fmaf(hv.x, w[k * 3 + 1], a1); a2 = fmaf(hv.x, w[k * 3 + 2], a2);
        a0 = fmaf(hv.y, w[k * 3 + 3], a0); a1 = fmaf(hv.y, w[k * 3 + 4], a1); a2 = fmaf(hv.y, w[k * 3 + 5], a2);
        a0 = fmaf(hv.z, w[k * 3 + 6], a0); a1 = fmaf(hv.z, w[k * 3 + 7], a1); a2 = fmaf(hv.z, w[k * 3 + 8], a2);
        a0 = fmaf(hv.w, w[k * 3 + 9], a0); a1 = fmaf(hv.w, w[k * 3 + 10], a1); a2 = fmaf(hv.w, w[k * 3 + 11], a2);
    }
    out[(size_t)i * 3 + 0] = (a0 + bout[0]) * 0.01f;
    out[(size_t)i * 3 + 1] = (a1 + bout[1]) * 0.01f;
    out[(size_t)i * 3 + 2] = (a2 + bout[2]) * 0.01f;
}

// ---------------- launch ------------------------------------------------------
extern "C" void kernel_launch(void* const* d_in, const int* in_sizes, int n_in,
                              void* d_out, int out_size, void* d_ws, size_t ws_size,
                              hipStream_t stream)
{
    const float* x    = (const float*)d_in[0];
    const float* z    = (const float*)d_in[1];
    const float* B0   = (const float*)d_in[2];
    const float* B1   = (const float*)d_in[3];
    const float* B2   = (const float*)d_in[4];
    const float* Wp   = (const float*)d_in[5];
    const float* bp   = (const float*)d_in[6];
    const float* Wl   = (const float*)d_in[7];
    const float* bl   = (const float*)d_in[8];
    const float* Wg   = (const float*)d_in[9];
    const float* bg   = (const float*)d_in[10];
    const float* Wb   = (const float*)d_in[11];
    const float* bb   = (const float*)d_in[12];
    const float* Wout = (const float*)d_in[13];
    const float* bout = (const float*)d_in[14];

    int n = in_sizes[0] / 3;  // 32768

    // workspace layout (float offsets)
    float* ws = (float*)d_ws;
    float* bias0  = ws;                    // 192
    float* gammaB = ws + 192;              // 768
    float* betaB  = ws + 960;              // 768
    size_t off = 1728;
    unsigned short* knn = (unsigned short*)(ws + off);  off += (size_t)n * 6;  // 12n u16
    float* relf = ws + off;                off += (size_t)n * 8;
    float* hA   = ws + off;                off += (size_t)n * 192;
    float* hB   = ws + off;                off += (size_t)n * 192;
    float* aggb = ws + off;                off += (size_t)n * 192;
    // aliases (lifetimes disjoint):
    double* pd  = (double*)hA;             // n*96 doubles = 24n floats < 192n, dead before gemm0 writes hA
    float*  pe  = hB;                      // n*64, dead after gemm0 reads it
    float4* xw  = (float4*)aggb;           // n float4, dead before first agg write

    prep_kernel<<<n / 256, 256, 0, stream>>>(x, B0, B1, B2, xw, pe, n);
    precompute_kernel<<<1, 256, 0, stream>>>(z, Wp, bp, Wg, bg, Wb, bb,
                                             bias0, gammaB, betaB);

    knn_kernel<<<dim3(n / 256, NSPLIT), 256, 0, stream>>>(xw, n, pd);
    knn_merge_kernel<<<n / 256, 256, 0, stream>>>(x, n, pd, knn, relf);

    // h0 = silu(pe @ Wp[:64] + bias0) -> hA   (pe cols 51..63 are zero)
    gemm_silu_kernel<false><<<n / 128, 256, 0, stream>>>(
        pe, nullptr, nullptr, Wp, bias0, nullptr, nullptr, hA);

    float* hcur = hA;
    float* hnxt = hB;
    for (int li = 0; li < 4; ++li) {
        agg_kernel<<<(size_t)n * 48 / 256, 256, 0, stream>>>(
            (const float4*)hcur, knn, (float4*)aggb, n);
        gemm_silu_kernel<true><<<n / 128, 256, 0, stream>>>(
            hcur, aggb, relf,
            Wl + (size_t)li * 390 * 192, bl + (size_t)li * 192,
            gammaB + (size_t)li * 192, betaB + (size_t)li * 192, hnxt);
        float* t = hcur; hcur = hnxt; hnxt = t;
    }

    out_kernel<<<n / 256, 256, 0, stream>>>((const float4*)hcur, Wout, bout,
                                            (float*)d_out, n);
}